// Round 1
// baseline (157.672 us; speedup 1.0000x reference)
//
#include <hip/hip_runtime.h>

#define HOURS 24

// Accumulator slots in workspace (doubles):
// 0: sum (yp-yt)^2 over all elements
// 1: sum (yp-yt)^2 over daytime elements
// 2: sum (p_pv - t_pv)^2 over rows
// 3: sum (p_pt - t_pt)^2 over rows
// 4: sum mse_win where valid
// 5: count valid

__global__ __launch_bounds__(256) void peakloss_main(
    const float* __restrict__ ypred, const float* __restrict__ ytrue,
    double* __restrict__ acc, int nrows) {
  float s_sq = 0.f, s_day = 0.f, s_pv = 0.f, s_pt = 0.f, s_shape = 0.f, s_valid = 0.f;

  const int stride = gridDim.x * blockDim.x;
  for (int r = blockIdx.x * blockDim.x + threadIdx.x; r < nrows; r += stride) {
    float t[HOURS], p[HOURS];
    const float4* t4 = (const float4*)(ytrue + (size_t)r * HOURS);
    const float4* p4 = (const float4*)(ypred + (size_t)r * HOURS);
#pragma unroll
    for (int k = 0; k < 6; ++k) {
      float4 a = t4[k];
      t[4 * k + 0] = a.x; t[4 * k + 1] = a.y; t[4 * k + 2] = a.z; t[4 * k + 3] = a.w;
      float4 b = p4[k];
      p[4 * k + 0] = b.x; p[4 * k + 1] = b.y; p[4 * k + 2] = b.z; p[4 * k + 3] = b.w;
    }

    // MSE terms
#pragma unroll
    for (int h = 0; h < HOURS; ++h) {
      float d = p[h] - t[h];
      float dd = d * d;
      s_sq += dd;
      if (h >= 6 && h <= 20) s_day += dd;
    }

    // daytime max + argmax (first-max semantics, matching jnp.argmax)
    float mt = -1e30f, mp = -1e30f;
    int idx = 6;
#pragma unroll
    for (int h = 6; h <= 20; ++h) {
      if (t[h] > mt) { mt = t[h]; idx = h; }
      mp = fmaxf(mp, p[h]);
    }

    // softmax over daytime hours, T = 0.1  => exp((y - max) * 10)
    float den_t = 0.f, nv_t = 0.f, nt_t = 0.f;
    float den_p = 0.f, nv_p = 0.f, nt_p = 0.f;
#pragma unroll
    for (int h = 6; h <= 20; ++h) {
      float et = __expf((t[h] - mt) * 10.f);
      den_t += et; nv_t += et * t[h]; nt_t += et * (float)h;
      float ep = __expf((p[h] - mp) * 10.f);
      den_p += ep; nv_p += ep * p[h]; nt_p += ep * (float)h;
    }
    float t_pv = nv_t / den_t, t_pt = nt_t / den_t;
    float p_pv = nv_p / den_p, p_pt = nt_p / den_p;
    float dv = p_pv - t_pv, dtm = p_pt - t_pt;
    s_pv += dv * dv;
    s_pt += dtm * dtm;

    // peak shape: window [idx-2, idx+3), idx in [6,20] so always in-bounds, len 5
    int ws = idx - 2;
    float tmax = -1e30f, pmax = -1e30f;
#pragma unroll
    for (int k = 0; k < 5; ++k) {
      tmax = fmaxf(tmax, t[ws + k]);
      pmax = fmaxf(pmax, p[ws + k]);
    }
    bool valid = tmax > 1e-6f;
    float tms = valid ? tmax : 1.0f;
    float pden = pmax + 1e-6f;
    float a = 0.f;
#pragma unroll
    for (int k = 0; k < 5; ++k) {
      float d = p[ws + k] / pden - t[ws + k] / tms;
      a += d * d;
    }
    if (valid) { s_shape += a * (1.0f / 5.0f); s_valid += 1.0f; }
  }

  // block reduction: wave shuffle, then across 4 waves via LDS, fp64 atomics
  float v[6] = {s_sq, s_day, s_pv, s_pt, s_shape, s_valid};
#pragma unroll
  for (int j = 0; j < 6; ++j) {
#pragma unroll
    for (int off = 32; off >= 1; off >>= 1) v[j] += __shfl_down(v[j], off, 64);
  }
  __shared__ float red[6][4];
  int lane = threadIdx.x & 63, wave = threadIdx.x >> 6;
  if (lane == 0) {
#pragma unroll
    for (int j = 0; j < 6; ++j) red[j][wave] = v[j];
  }
  __syncthreads();
  if (threadIdx.x == 0) {
#pragma unroll
    for (int j = 0; j < 6; ++j) {
      double s = (double)red[j][0] + (double)red[j][1] + (double)red[j][2] + (double)red[j][3];
      atomicAdd(&acc[j], s);
    }
  }
}

__global__ void peakloss_finalize(const double* __restrict__ acc,
                                  float* __restrict__ out,
                                  double inv_BS, double inv_BD) {
  double L_overall = acc[0] * inv_BS;
  double L_day     = acc[1] * inv_BS;          // weighted_mse - L_overall
  double L_pv      = acc[2] * inv_BD;
  double L_pt      = acc[3] * inv_BD;
  double L_shape   = acc[4] / (acc[5] + 1e-6);
  double total = 1.0 * L_overall + 2.0 * L_pv + 1.0 * L_pt + 0.5 * L_shape + 0.5 * L_day;
  out[0] = (float)total;
}

extern "C" void kernel_launch(void* const* d_in, const int* in_sizes, int n_in,
                              void* d_out, int out_size, void* d_ws, size_t ws_size,
                              hipStream_t stream) {
  const float* ypred = (const float*)d_in[0];
  const float* ytrue = (const float*)d_in[1];
  float* out = (float*)d_out;
  double* acc = (double*)d_ws;

  long long N = in_sizes[0];          // B * S
  int nrows = (int)(N / HOURS);       // B * D

  hipMemsetAsync(acc, 0, 6 * sizeof(double), stream);

  int block = 256;
  int grid = (nrows + block - 1) / block;
  if (grid > 2048) grid = 2048;
  peakloss_main<<<grid, block, 0, stream>>>(ypred, ytrue, acc, nrows);

  double inv_BS = 1.0 / (double)N;
  double inv_BD = 1.0 / (double)nrows;
  peakloss_finalize<<<1, 1, 0, stream>>>(acc, out, inv_BS, inv_BD);
}